// Round 11
// baseline (170.058 us; speedup 1.0000x reference)
//
#include <hip/hip_runtime.h>
#include <math.h>

#define T_LEN 6000
#define NROWS 4096          // B*C = 512*8
#define NCH 8
#define F_BINS 129
#define CF (NCH*F_BINS)     // 1032
#define REG_EPS 1e-7f

typedef _Float16 half8 __attribute__((ext_vector_type(8)));
typedef _Float16 half4_t __attribute__((ext_vector_type(4)));
typedef float f32x4 __attribute__((ext_vector_type(4)));

// ---------------- Kernel A: DFT basis, pre-packed in MFMA B-fragment layout ----------------
// Bf[((nt*8+kk)*64+lane)] is a half8: element e -> B[k][n] with n=16*nt+(lane&15),
// k=32*kk+8*(lane>>4)+e. n<129: cos(2*pi*n*k/256); n>=129: sin(2*pi*(n-128)*k/256).
__global__ __launch_bounds__(256) void basis_kernel(_Float16* __restrict__ Bf) {
  int g = blockIdx.x * 256 + threadIdx.x;   // 0..8191 = (nt*8+kk)*64+lane
  int lane = g & 63;
  int ntkk = g >> 6;
  int nt = ntkk >> 3, kk = ntkk & 7;
  int n = 16 * nt + (lane & 15);
  int k0 = 32 * kk + 8 * (lane >> 4);
  half8 out;
  #pragma unroll
  for (int e = 0; e < 8; ++e) {
    int k = k0 + e;
    int m = (n < 129) ? ((n * k) & 255) : (((n - 128) * k) & 255);
    float ang = (float)m * (6.283185307179586f / 256.f);
    float v = (n < 129) ? cosf(ang) : sinf(ang);
    out[e] = (_Float16)v;
  }
  *(half8*)(Bf + (size_t)g * 8) = out;
}

// ---------------- Kernel B: Welch PSD + row mean via im2col MFMA GEMM ----------------
// 8 waves; wave w owns N-tiles {2w,2w+1}; bf[2][8] persistent (loaded once/block).
// DOUBLE-BUFFERED LDS pipeline (2 barriers/row): iteration jr overlaps
// {stage row jr+1 -> xh[buf^1], issue loads row jr+2} with GEMM(row jr, xh[buf]).
// rowm triple-buffered (phase-1 write has no barrier vs prev epilogue read).
#define PSD_ROWS 8
__global__ __launch_bounds__(512, 4) void psd_kernel(const float* __restrict__ x,
                                                     const _Float16* __restrict__ Bf,
                                                     float* __restrict__ psd,
                                                     float* __restrict__ means) {
  int tid = threadIdx.x;
  int lane = tid & 63;
  int w = tid >> 6;          // 0..7
  int l15 = lane & 15, l4 = lane >> 4;
  __shared__ __align__(16) _Float16 xh[2][6272];
  __shared__ float colsum[256];
  __shared__ float rowm[3][8];

  // persistent B fragments: nt = 2w+i (coalesced fragment-layout loads)
  half8 bf[2][8];
  #pragma unroll
  for (int i = 0; i < 2; ++i) {
    const _Float16* bb = Bf + (size_t)(((2 * w + i) * 8) * 64 + lane) * 8;
    #pragma unroll
    for (int kk = 0; kk < 8; ++kk)
      bf[i][kk] = *(const half8*)(bb + (size_t)kk * 512);
  }

  int r0 = blockIdx.x * PSD_ROWS;
  float4 v[4];
  // prologue: load + stage row 0 (rowm slot 0), then load row 1
  {
    const float* xr = x + (size_t)r0 * T_LEN;
    #pragma unroll
    for (int j = 0; j < 4; ++j) {
      int c = tid + 512 * j;
      v[j] = (c < 1500) ? ((const float4*)xr)[c] : make_float4(0.f, 0.f, 0.f, 0.f);
    }
    float rs = 0.f;
    #pragma unroll
    for (int j = 0; j < 4; ++j) {
      int c = tid + 512 * j;
      if (c < 1568) {
        float4 q = v[j];
        rs += q.x + q.y + q.z + q.w;
        half4_t h = { (_Float16)q.x, (_Float16)q.y, (_Float16)q.z, (_Float16)q.w };
        int byte = 8 * c;
        byte ^= ((byte >> 8) & 7) << 4;
        *(half4_t*)((char*)xh[0] + byte) = h;
      }
    }
    #pragma unroll
    for (int off = 32; off >= 1; off >>= 1) rs += __shfl_xor(rs, off);
    if (lane == 0) rowm[0][w] = rs;
    const float* x1 = x + (size_t)(r0 + 1) * T_LEN;
    #pragma unroll
    for (int j = 0; j < 4; ++j) {
      int c = tid + 512 * j;
      v[j] = (c < 1500) ? ((const float4*)x1)[c] : make_float4(0.f, 0.f, 0.f, 0.f);
    }
  }
  __syncthreads();                              // xh[0] visible

  for (int jr = 0; jr < PSD_ROWS; ++jr) {
    int r = r0 + jr;
    const char* xcur = (const char*)xh[jr & 1];
    // ---- phase 1: stage row jr+1 into other buffer; issue loads row jr+2 ----
    if (jr + 1 < PSD_ROWS) {
      char* xnxt = (char*)xh[(jr + 1) & 1];
      float rs = 0.f;
      #pragma unroll
      for (int j = 0; j < 4; ++j) {
        int c = tid + 512 * j;
        if (c < 1568) {
          float4 q = v[j];
          rs += q.x + q.y + q.z + q.w;
          half4_t h = { (_Float16)q.x, (_Float16)q.y, (_Float16)q.z, (_Float16)q.w };
          int byte = 8 * c;
          byte ^= ((byte >> 8) & 7) << 4;
          *(half4_t*)(xnxt + byte) = h;
        }
      }
      if (jr + 2 < PSD_ROWS) {
        const float* xn = x + (size_t)(r + 2) * T_LEN;
        #pragma unroll
        for (int j = 0; j < 4; ++j) {
          int c = tid + 512 * j;
          v[j] = (c < 1500) ? ((const float4*)xn)[c] : make_float4(0.f, 0.f, 0.f, 0.f);
        }
      }
      #pragma unroll
      for (int off = 32; off >= 1; off >>= 1) rs += __shfl_xor(rs, off);
      if (lane == 0) rowm[(jr + 1) % 3][w] = rs;
    }
    // ---- GEMM on xcur (overlaps the stage/load latency above) ----
    f32x4 acc[2][3];
    #pragma unroll
    for (int i = 0; i < 2; ++i)
      #pragma unroll
      for (int mt = 0; mt < 3; ++mt)
        acc[i][mt] = (f32x4){0.f, 0.f, 0.f, 0.f};
    #pragma unroll
    for (int kk = 0; kk < 8; ++kk) {
      half8 a[3];
      #pragma unroll
      for (int mt = 0; mt < 3; ++mt) {
        int ab = 4096 * mt + 256 * l15 + 64 * kk + 16 * l4;
        ab ^= ((ab >> 8) & 7) << 4;
        a[mt] = *(const half8*)(xcur + ab);
      }
      #pragma unroll
      for (int mt = 0; mt < 3; ++mt) {
        acc[0][mt] = __builtin_amdgcn_mfma_f32_16x16x32_f16(a[mt], bf[0][kk], acc[0][mt], 0, 0, 0);
        acc[1][mt] = __builtin_amdgcn_mfma_f32_16x16x32_f16(a[mt], bf[1][kk], acc[1][mt], 0, 0, 0);
      }
    }
    // per-lane column partials; C/D: row m = 16*mt+4*l4+j, col n = 16*nt+l15
    float s0, s1;
    #pragma unroll
    for (int i = 0; i < 2; ++i) {
      float t = 0.f;
      #pragma unroll
      for (int j = 0; j < 4; ++j) {
        t += acc[i][0][j] * acc[i][0][j];
        t += acc[i][1][j] * acc[i][1][j];
        if (4 * l4 + j < 13) t += acc[i][2][j] * acc[i][2][j];  // mask m>=45
      }
      t += __shfl_xor(t, 16);
      t += __shfl_xor(t, 32);
      if (i == 0) s0 = t; else s1 = t;
    }
    __syncthreads();                            // (A) stage visible, GEMM reads done
    if (l4 == 0) {
      colsum[16 * (2 * w + 0) + l15] = s0;
      colsum[16 * (2 * w + 1) + l15] = s1;
    }
    __syncthreads();                            // (B) colsum visible
    if (tid < F_BINS) {
      float vv;
      if (tid == 0) vv = 0.f;                                   // detrended DC
      else if (tid == 128) vv = colsum[128] * (1.f / 11520.f);  // Nyquist, no doubling
      else vv = (colsum[tid] + colsum[tid + 128]) * (1.f / 5760.f);
      psd[(size_t)r * F_BINS + tid] = vv + REG_EPS;
    }
    if (tid == 0) {
      float ms = 0.f;
      #pragma unroll
      for (int q = 0; q < 8; ++q) ms += rowm[jr % 3][q];
      means[r] = ms * (1.f / (float)T_LEN);
    }
  }
}

// ---------------- Kernel C: barycenter over batch (unchanged) ----------------
__global__ __launch_bounds__(256) void bary_kernel(const float* __restrict__ psd,
                                                   float* __restrict__ bary) {
  int cf = blockIdx.x;
  int tid = threadIdx.x;
  float s = sqrtf(psd[(size_t)tid * CF + cf]) +
            sqrtf(psd[(size_t)(tid + 256) * CF + cf]);
  #pragma unroll
  for (int off = 32; off >= 1; off >>= 1) s += __shfl_down(s, off);
  __shared__ float wsum[4];
  if ((tid & 63) == 0) wsum[tid >> 6] = s;
  __syncthreads();
  if (tid == 0) {
    float tot = (wsum[0] + wsum[1] + wsum[2] + wsum[3]) * (1.f / (float)F_BINS);
    bary[cf] = tot * tot;
  }
}

// ---------------- Kernel D: filter H (unchanged) ----------------
__global__ __launch_bounds__(256) void filt_kernel(const float* __restrict__ psd,
                                                   const float* __restrict__ bary,
                                                   float* __restrict__ H) {
  int rc = blockIdx.x;
  int c = rc & (NCH - 1);
  int t = threadIdx.x;
  __shared__ float dv[F_BINS];
  __shared__ float hv[F_BINS];
  if (t < F_BINS)
    dv[t] = sqrtf(bary[c * F_BINS + t] / psd[(size_t)rc * F_BINS + t]);
  __syncthreads();
  if (t < F_BINS) {
    float ct, st;
    __sincosf(6.283185307179586f * (float)t * (1.f / 256.f), &st, &ct);
    float cr = ct, ci = st;
    float acc = 0.f;
    for (int k = 1; k <= 127; ++k) {
      acc = fmaf(dv[k], cr, acc);
      float nr = cr * ct - ci * st;
      ci = cr * st + ci * ct;
      cr = nr;
    }
    float val = dv[0] + ((t & 1) ? -dv[128] : dv[128]) + 2.f * acc;
    hv[t] = val * (1.f / 256.f);
  }
  __syncthreads();
  int idx = t - 127; if (idx < 0) idx = -idx;
  H[(size_t)rc * 256 + t] = hv[idx];
}

// ---------------- Kernel E: depthwise conv as per-row im2col MFMA GEMM (unchanged) ----------------
#define XH_N 6528
#define BSTRIDE 296
__global__ __launch_bounds__(384, 1) void conv_kernel(const float* __restrict__ x,
                                                      const float* __restrict__ means,
                                                      const float* __restrict__ Hg,
                                                      float* __restrict__ y) {
  int rc = blockIdx.x;
  int tid = threadIdx.x;
  int lane = tid & 63;
  int w = tid >> 6;
  __shared__ __align__(16) _Float16 xh[XH_N];
  __shared__ __align__(16) _Float16 Bp[16 * BSTRIDE];
  const float* xr = x + (size_t)rc * T_LEN;
  const float* Hrow = Hg + (size_t)rc * 256;
  float mean = means[rc];
  // xh: half4 chunk q covers halves [4q,4q+4) = x float4 chunk q-32 (minus mean)
  #pragma unroll
  for (int j = 0; j < 5; ++j) {
    int q = tid + 384 * j;
    if (q < 1632) {
      int c = q - 32;
      half4_t h;
      if (c >= 0 && c < 1500) {
        float4 vv = ((const float4*)xr)[c];
        h = (half4_t){ (_Float16)(vv.x - mean), (_Float16)(vv.y - mean),
                       (_Float16)(vv.z - mean), (_Float16)(vv.w - mean) };
      } else {
        h = (half4_t){ (_Float16)0.f, (_Float16)0.f, (_Float16)0.f, (_Float16)0.f };
      }
      *(half4_t*)((char*)xh + 8 * q) = h;
    }
  }
  // Bp: idx = chunk*16+n; thread writes half4 at Bp[n][4*qq..] = H[4*qq-n-1 ..]
  #pragma unroll
  for (int j = 0; j < 3; ++j) {
    int idx = tid + 384 * j;        // < 1152 = 72*16 exactly
    int n = idx & 15;
    int qq = idx >> 4;              // 0..71
    int s0 = 4 * qq - n - 1;
    half4_t h;
    #pragma unroll
    for (int e = 0; e < 4; ++e) {
      int s = s0 + e;
      float hv = (s >= 0 && s < 256) ? Hrow[s] : 0.f;
      h[e] = (_Float16)hv;
    }
    *(half4_t*)((char*)Bp + (size_t)n * (2 * BSTRIDE) + 8 * qq) = h;
  }
  __syncthreads();

  int l15 = lane & 15, l4 = lane >> 4;
  f32x4 acc0 = {0.f,0.f,0.f,0.f}, acc1 = {0.f,0.f,0.f,0.f};
  f32x4 acc2 = {0.f,0.f,0.f,0.f}, acc3 = {0.f,0.f,0.f,0.f};
  const _Float16* bbase = &Bp[BSTRIDE * l15 + 8 * l4];
  const _Float16* abase = &xh[16 * l15 + 8 * l4 + 1024 * w];
  #pragma unroll
  for (int kk = 0; kk < 9; ++kk) {
    half8 b = *(const half8*)(bbase + 32 * kk);
    half8 a0 = *(const half8*)(abase + 32 * kk);
    half8 a1 = *(const half8*)(abase + 256 + 32 * kk);
    half8 a2 = *(const half8*)(abase + 512 + 32 * kk);
    half8 a3 = *(const half8*)(abase + 768 + 32 * kk);
    acc0 = __builtin_amdgcn_mfma_f32_16x16x32_f16(a0, b, acc0, 0, 0, 0);
    acc1 = __builtin_amdgcn_mfma_f32_16x16x32_f16(a1, b, acc1, 0, 0, 0);
    acc2 = __builtin_amdgcn_mfma_f32_16x16x32_f16(a2, b, acc2, 0, 0, 0);
    acc3 = __builtin_amdgcn_mfma_f32_16x16x32_f16(a3, b, acc3, 0, 0, 0);
  }
  float* yr = y + (size_t)rc * T_LEN;
  #pragma unroll
  for (int i = 0; i < 4; ++i) {
    f32x4 a = (i == 0) ? acc0 : (i == 1) ? acc1 : (i == 2) ? acc2 : acc3;
    int mt = 4 * w + i;
    #pragma unroll
    for (int j = 0; j < 4; ++j) {
      int m = 16 * mt + 4 * l4 + j;
      if (m < 375) yr[16 * m + l15] = a[j];
    }
  }
}

extern "C" void kernel_launch(void* const* d_in, const int* in_sizes, int n_in,
                              void* d_out, int out_size, void* d_ws, size_t ws_size,
                              hipStream_t stream) {
  const float* x = (const float*)d_in[0];
  float* out = (float*)d_out;
  float* psd   = (float*)d_ws;                         //   528,384 f
  float* bary  = psd + (size_t)NROWS * F_BINS;         //     1,032 f
  float* H     = bary + CF;                            // 1,048,576 f
  float* means = H + (size_t)NROWS * 256;              //     4,096 f
  _Float16* Bf = (_Float16*)(means + NROWS);           //    65,536 f16 (16B-aligned)
  basis_kernel<<<32, 256, 0, stream>>>(Bf);
  psd_kernel<<<NROWS / PSD_ROWS, 512, 0, stream>>>(x, Bf, psd, means);
  bary_kernel<<<CF, 256, 0, stream>>>(psd, bary);
  filt_kernel<<<NROWS, 256, 0, stream>>>(psd, bary, H);
  conv_kernel<<<NROWS, 384, 0, stream>>>(x, means, H, out);
}

// Round 12
// 120.938 us; speedup vs baseline: 1.4062x; 1.4062x over previous
//
#include <hip/hip_runtime.h>
#include <math.h>

#define T_LEN 6000
#define NROWS 4096          // B*C = 512*8
#define NCH 8
#define F_BINS 129
#define CF (NCH*F_BINS)     // 1032
#define REG_EPS 1e-7f

typedef _Float16 half8 __attribute__((ext_vector_type(8)));
typedef _Float16 half4_t __attribute__((ext_vector_type(4)));
typedef float f32x4 __attribute__((ext_vector_type(4)));

// ---------------- Kernel A: DFT basis, pre-packed in MFMA B-fragment layout ----------------
// Bf[((nt*8+kk)*64+lane)] is a half8: element e -> B[k][n] with n=16*nt+(lane&15),
// k=32*kk+8*(lane>>4)+e. n<129: cos(2*pi*n*k/256); n>=129: sin(2*pi*(n-128)*k/256).
__global__ __launch_bounds__(256) void basis_kernel(_Float16* __restrict__ Bf) {
  int g = blockIdx.x * 256 + threadIdx.x;   // 0..8191 = (nt*8+kk)*64+lane
  int lane = g & 63;
  int ntkk = g >> 6;
  int nt = ntkk >> 3, kk = ntkk & 7;
  int n = 16 * nt + (lane & 15);
  int k0 = 32 * kk + 8 * (lane >> 4);
  half8 out;
  #pragma unroll
  for (int e = 0; e < 8; ++e) {
    int k = k0 + e;
    int m = (n < 129) ? ((n * k) & 255) : (((n - 128) * k) & 255);
    float ang = (float)m * (6.283185307179586f / 256.f);
    float v = (n < 129) ? cosf(ang) : sinf(ang);
    out[e] = (_Float16)v;
  }
  *(half8*)(Bf + (size_t)g * 8) = out;
}

// ---------------- Kernel B: Welch PSD + row mean via im2col MFMA GEMM ----------------
// 8 waves; wave w owns N-tiles {2w,2w+1}; bf[2][8] persistent (loaded once/block).
// DOUBLE-BUFFERED LDS pipeline (2 barriers/row): iteration jr overlaps
// {stage row jr+1 -> xh[buf^1], issue loads row jr+2} with GEMM(row jr, xh[buf]).
// rowm triple-buffered (phase-1 write has no barrier vs prev epilogue read).
// __launch_bounds__(512,2): round 11's (512,4) capped VGPR at 64 (< ~124 live)
// and spilled bf[] to scratch (FETCH +85MB, WRITE +37MB). (512,2) allocs ~84
// VGPR + AGPR accs with zero spill (rounds 9/10 evidence).
#define PSD_ROWS 8
__global__ __launch_bounds__(512, 2) void psd_kernel(const float* __restrict__ x,
                                                     const _Float16* __restrict__ Bf,
                                                     float* __restrict__ psd,
                                                     float* __restrict__ means) {
  int tid = threadIdx.x;
  int lane = tid & 63;
  int w = tid >> 6;          // 0..7
  int l15 = lane & 15, l4 = lane >> 4;
  __shared__ __align__(16) _Float16 xh[2][6272];
  __shared__ float colsum[256];
  __shared__ float rowm[3][8];

  // persistent B fragments: nt = 2w+i (coalesced fragment-layout loads)
  half8 bf[2][8];
  #pragma unroll
  for (int i = 0; i < 2; ++i) {
    const _Float16* bb = Bf + (size_t)(((2 * w + i) * 8) * 64 + lane) * 8;
    #pragma unroll
    for (int kk = 0; kk < 8; ++kk)
      bf[i][kk] = *(const half8*)(bb + (size_t)kk * 512);
  }

  int r0 = blockIdx.x * PSD_ROWS;
  float4 v[4];
  // prologue: load + stage row 0 (rowm slot 0), then load row 1
  {
    const float* xr = x + (size_t)r0 * T_LEN;
    #pragma unroll
    for (int j = 0; j < 4; ++j) {
      int c = tid + 512 * j;
      v[j] = (c < 1500) ? ((const float4*)xr)[c] : make_float4(0.f, 0.f, 0.f, 0.f);
    }
    float rs = 0.f;
    #pragma unroll
    for (int j = 0; j < 4; ++j) {
      int c = tid + 512 * j;
      if (c < 1568) {
        float4 q = v[j];
        rs += q.x + q.y + q.z + q.w;
        half4_t h = { (_Float16)q.x, (_Float16)q.y, (_Float16)q.z, (_Float16)q.w };
        int byte = 8 * c;
        byte ^= ((byte >> 8) & 7) << 4;
        *(half4_t*)((char*)xh[0] + byte) = h;
      }
    }
    #pragma unroll
    for (int off = 32; off >= 1; off >>= 1) rs += __shfl_xor(rs, off);
    if (lane == 0) rowm[0][w] = rs;
    const float* x1 = x + (size_t)(r0 + 1) * T_LEN;
    #pragma unroll
    for (int j = 0; j < 4; ++j) {
      int c = tid + 512 * j;
      v[j] = (c < 1500) ? ((const float4*)x1)[c] : make_float4(0.f, 0.f, 0.f, 0.f);
    }
  }
  __syncthreads();                              // xh[0] visible

  for (int jr = 0; jr < PSD_ROWS; ++jr) {
    int r = r0 + jr;
    const char* xcur = (const char*)xh[jr & 1];
    // ---- phase 1: stage row jr+1 into other buffer; issue loads row jr+2 ----
    if (jr + 1 < PSD_ROWS) {
      char* xnxt = (char*)xh[(jr + 1) & 1];
      float rs = 0.f;
      #pragma unroll
      for (int j = 0; j < 4; ++j) {
        int c = tid + 512 * j;
        if (c < 1568) {
          float4 q = v[j];
          rs += q.x + q.y + q.z + q.w;
          half4_t h = { (_Float16)q.x, (_Float16)q.y, (_Float16)q.z, (_Float16)q.w };
          int byte = 8 * c;
          byte ^= ((byte >> 8) & 7) << 4;
          *(half4_t*)(xnxt + byte) = h;
        }
      }
      if (jr + 2 < PSD_ROWS) {
        const float* xn = x + (size_t)(r + 2) * T_LEN;
        #pragma unroll
        for (int j = 0; j < 4; ++j) {
          int c = tid + 512 * j;
          v[j] = (c < 1500) ? ((const float4*)xn)[c] : make_float4(0.f, 0.f, 0.f, 0.f);
        }
      }
      #pragma unroll
      for (int off = 32; off >= 1; off >>= 1) rs += __shfl_xor(rs, off);
      if (lane == 0) rowm[(jr + 1) % 3][w] = rs;
    }
    // ---- GEMM on xcur (overlaps the stage/load latency above) ----
    f32x4 acc[2][3];
    #pragma unroll
    for (int i = 0; i < 2; ++i)
      #pragma unroll
      for (int mt = 0; mt < 3; ++mt)
        acc[i][mt] = (f32x4){0.f, 0.f, 0.f, 0.f};
    #pragma unroll
    for (int kk = 0; kk < 8; ++kk) {
      half8 a[3];
      #pragma unroll
      for (int mt = 0; mt < 3; ++mt) {
        int ab = 4096 * mt + 256 * l15 + 64 * kk + 16 * l4;
        ab ^= ((ab >> 8) & 7) << 4;
        a[mt] = *(const half8*)(xcur + ab);
      }
      #pragma unroll
      for (int mt = 0; mt < 3; ++mt) {
        acc[0][mt] = __builtin_amdgcn_mfma_f32_16x16x32_f16(a[mt], bf[0][kk], acc[0][mt], 0, 0, 0);
        acc[1][mt] = __builtin_amdgcn_mfma_f32_16x16x32_f16(a[mt], bf[1][kk], acc[1][mt], 0, 0, 0);
      }
    }
    // per-lane column partials; C/D: row m = 16*mt+4*l4+j, col n = 16*nt+l15
    float s0, s1;
    #pragma unroll
    for (int i = 0; i < 2; ++i) {
      float t = 0.f;
      #pragma unroll
      for (int j = 0; j < 4; ++j) {
        t += acc[i][0][j] * acc[i][0][j];
        t += acc[i][1][j] * acc[i][1][j];
        if (4 * l4 + j < 13) t += acc[i][2][j] * acc[i][2][j];  // mask m>=45
      }
      t += __shfl_xor(t, 16);
      t += __shfl_xor(t, 32);
      if (i == 0) s0 = t; else s1 = t;
    }
    __syncthreads();                            // (A) stage visible, GEMM reads done
    if (l4 == 0) {
      colsum[16 * (2 * w + 0) + l15] = s0;
      colsum[16 * (2 * w + 1) + l15] = s1;
    }
    __syncthreads();                            // (B) colsum visible
    if (tid < F_BINS) {
      float vv;
      if (tid == 0) vv = 0.f;                                   // detrended DC
      else if (tid == 128) vv = colsum[128] * (1.f / 11520.f);  // Nyquist, no doubling
      else vv = (colsum[tid] + colsum[tid + 128]) * (1.f / 5760.f);
      psd[(size_t)r * F_BINS + tid] = vv + REG_EPS;
    }
    if (tid == 0) {
      float ms = 0.f;
      #pragma unroll
      for (int q = 0; q < 8; ++q) ms += rowm[jr % 3][q];
      means[r] = ms * (1.f / (float)T_LEN);
    }
  }
}

// ---------------- Kernel C: barycenter over batch (unchanged) ----------------
__global__ __launch_bounds__(256) void bary_kernel(const float* __restrict__ psd,
                                                   float* __restrict__ bary) {
  int cf = blockIdx.x;
  int tid = threadIdx.x;
  float s = sqrtf(psd[(size_t)tid * CF + cf]) +
            sqrtf(psd[(size_t)(tid + 256) * CF + cf]);
  #pragma unroll
  for (int off = 32; off >= 1; off >>= 1) s += __shfl_down(s, off);
  __shared__ float wsum[4];
  if ((tid & 63) == 0) wsum[tid >> 6] = s;
  __syncthreads();
  if (tid == 0) {
    float tot = (wsum[0] + wsum[1] + wsum[2] + wsum[3]) * (1.f / (float)F_BINS);
    bary[cf] = tot * tot;
  }
}

// ---------------- Kernel D: filter H (unchanged) ----------------
__global__ __launch_bounds__(256) void filt_kernel(const float* __restrict__ psd,
                                                   const float* __restrict__ bary,
                                                   float* __restrict__ H) {
  int rc = blockIdx.x;
  int c = rc & (NCH - 1);
  int t = threadIdx.x;
  __shared__ float dv[F_BINS];
  __shared__ float hv[F_BINS];
  if (t < F_BINS)
    dv[t] = sqrtf(bary[c * F_BINS + t] / psd[(size_t)rc * F_BINS + t]);
  __syncthreads();
  if (t < F_BINS) {
    float ct, st;
    __sincosf(6.283185307179586f * (float)t * (1.f / 256.f), &st, &ct);
    float cr = ct, ci = st;
    float acc = 0.f;
    for (int k = 1; k <= 127; ++k) {
      acc = fmaf(dv[k], cr, acc);
      float nr = cr * ct - ci * st;
      ci = cr * st + ci * ct;
      cr = nr;
    }
    float val = dv[0] + ((t & 1) ? -dv[128] : dv[128]) + 2.f * acc;
    hv[t] = val * (1.f / 256.f);
  }
  __syncthreads();
  int idx = t - 127; if (idx < 0) idx = -idx;
  H[(size_t)rc * 256 + t] = hv[idx];
}

// ---------------- Kernel E: depthwise conv as per-row im2col MFMA GEMM (unchanged) ----------------
#define XH_N 6528
#define BSTRIDE 296
__global__ __launch_bounds__(384, 1) void conv_kernel(const float* __restrict__ x,
                                                      const float* __restrict__ means,
                                                      const float* __restrict__ Hg,
                                                      float* __restrict__ y) {
  int rc = blockIdx.x;
  int tid = threadIdx.x;
  int lane = tid & 63;
  int w = tid >> 6;
  __shared__ __align__(16) _Float16 xh[XH_N];
  __shared__ __align__(16) _Float16 Bp[16 * BSTRIDE];
  const float* xr = x + (size_t)rc * T_LEN;
  const float* Hrow = Hg + (size_t)rc * 256;
  float mean = means[rc];
  // xh: half4 chunk q covers halves [4q,4q+4) = x float4 chunk q-32 (minus mean)
  #pragma unroll
  for (int j = 0; j < 5; ++j) {
    int q = tid + 384 * j;
    if (q < 1632) {
      int c = q - 32;
      half4_t h;
      if (c >= 0 && c < 1500) {
        float4 vv = ((const float4*)xr)[c];
        h = (half4_t){ (_Float16)(vv.x - mean), (_Float16)(vv.y - mean),
                       (_Float16)(vv.z - mean), (_Float16)(vv.w - mean) };
      } else {
        h = (half4_t){ (_Float16)0.f, (_Float16)0.f, (_Float16)0.f, (_Float16)0.f };
      }
      *(half4_t*)((char*)xh + 8 * q) = h;
    }
  }
  // Bp: idx = chunk*16+n; thread writes half4 at Bp[n][4*qq..] = H[4*qq-n-1 ..]
  #pragma unroll
  for (int j = 0; j < 3; ++j) {
    int idx = tid + 384 * j;        // < 1152 = 72*16 exactly
    int n = idx & 15;
    int qq = idx >> 4;              // 0..71
    int s0 = 4 * qq - n - 1;
    half4_t h;
    #pragma unroll
    for (int e = 0; e < 4; ++e) {
      int s = s0 + e;
      float hv = (s >= 0 && s < 256) ? Hrow[s] : 0.f;
      h[e] = (_Float16)hv;
    }
    *(half4_t*)((char*)Bp + (size_t)n * (2 * BSTRIDE) + 8 * qq) = h;
  }
  __syncthreads();

  int l15 = lane & 15, l4 = lane >> 4;
  f32x4 acc0 = {0.f,0.f,0.f,0.f}, acc1 = {0.f,0.f,0.f,0.f};
  f32x4 acc2 = {0.f,0.f,0.f,0.f}, acc3 = {0.f,0.f,0.f,0.f};
  const _Float16* bbase = &Bp[BSTRIDE * l15 + 8 * l4];
  const _Float16* abase = &xh[16 * l15 + 8 * l4 + 1024 * w];
  #pragma unroll
  for (int kk = 0; kk < 9; ++kk) {
    half8 b = *(const half8*)(bbase + 32 * kk);
    half8 a0 = *(const half8*)(abase + 32 * kk);
    half8 a1 = *(const half8*)(abase + 256 + 32 * kk);
    half8 a2 = *(const half8*)(abase + 512 + 32 * kk);
    half8 a3 = *(const half8*)(abase + 768 + 32 * kk);
    acc0 = __builtin_amdgcn_mfma_f32_16x16x32_f16(a0, b, acc0, 0, 0, 0);
    acc1 = __builtin_amdgcn_mfma_f32_16x16x32_f16(a1, b, acc1, 0, 0, 0);
    acc2 = __builtin_amdgcn_mfma_f32_16x16x32_f16(a2, b, acc2, 0, 0, 0);
    acc3 = __builtin_amdgcn_mfma_f32_16x16x32_f16(a3, b, acc3, 0, 0, 0);
  }
  float* yr = y + (size_t)rc * T_LEN;
  #pragma unroll
  for (int i = 0; i < 4; ++i) {
    f32x4 a = (i == 0) ? acc0 : (i == 1) ? acc1 : (i == 2) ? acc2 : acc3;
    int mt = 4 * w + i;
    #pragma unroll
    for (int j = 0; j < 4; ++j) {
      int m = 16 * mt + 4 * l4 + j;
      if (m < 375) yr[16 * m + l15] = a[j];
    }
  }
}

extern "C" void kernel_launch(void* const* d_in, const int* in_sizes, int n_in,
                              void* d_out, int out_size, void* d_ws, size_t ws_size,
                              hipStream_t stream) {
  const float* x = (const float*)d_in[0];
  float* out = (float*)d_out;
  float* psd   = (float*)d_ws;                         //   528,384 f
  float* bary  = psd + (size_t)NROWS * F_BINS;         //     1,032 f
  float* H     = bary + CF;                            // 1,048,576 f
  float* means = H + (size_t)NROWS * 256;              //     4,096 f
  _Float16* Bf = (_Float16*)(means + NROWS);           //    65,536 f16 (16B-aligned)
  basis_kernel<<<32, 256, 0, stream>>>(Bf);
  psd_kernel<<<NROWS / PSD_ROWS, 512, 0, stream>>>(x, Bf, psd, means);
  bary_kernel<<<CF, 256, 0, stream>>>(psd, bary);
  filt_kernel<<<NROWS, 256, 0, stream>>>(psd, bary, H);
  conv_kernel<<<NROWS, 384, 0, stream>>>(x, means, H, out);
}

// Round 13
// 118.277 us; speedup vs baseline: 1.4378x; 1.0225x over previous
//
#include <hip/hip_runtime.h>
#include <math.h>

#define T_LEN 6000
#define NROWS 4096          // B*C = 512*8
#define NCH 8
#define F_BINS 129
#define CF (NCH*F_BINS)     // 1032
#define REG_EPS 1e-7f

typedef _Float16 half8 __attribute__((ext_vector_type(8)));
typedef _Float16 half4_t __attribute__((ext_vector_type(4)));
typedef float f32x4 __attribute__((ext_vector_type(4)));

// ---------------- Kernel B: Welch PSD + row mean via im2col MFMA GEMM ----------------
// 8 waves; wave w owns N-tiles {2w,2w+1}; bf[2][8] persistent, computed IN-KERNEL
// (128 sincosf per thread, once per block, amortized over 8 rows) -- basis kernel
// and its launch gap removed. DOUBLE-BUFFERED LDS pipeline (2 barriers/row).
// __launch_bounds__(512,2): (512,4) capped VGPR at 64 and spilled (round-11 evidence).
#define PSD_ROWS 8
__global__ __launch_bounds__(512, 2) void psd_kernel(const float* __restrict__ x,
                                                     float* __restrict__ psd,
                                                     float* __restrict__ means) {
  int tid = threadIdx.x;
  int lane = tid & 63;
  int w = tid >> 6;          // 0..7
  int l15 = lane & 15, l4 = lane >> 4;
  __shared__ __align__(16) _Float16 xh[2][6272];
  __shared__ float colsum[256];
  __shared__ float rowm[3][8];

  // persistent B fragments computed directly: nt = 2w+i, col n = 16*nt+l15,
  // k = 32*kk+8*l4+e; value = cos(2*pi*n*k/256) for n<129, sin(2*pi*(n-128)*k/256) else.
  half8 bf[2][8];
  #pragma unroll
  for (int i = 0; i < 2; ++i) {
    int n = 16 * (2 * w + i) + l15;
    int nn = (n < 129) ? n : (n - 128);
    for (int kk = 0; kk < 8; ++kk) {
      half8 hb;
      for (int e = 0; e < 8; ++e) {
        int k = 32 * kk + 8 * l4 + e;
        float ang = (float)((nn * k) & 255) * (6.283185307179586f / 256.f);
        float s, c;
        __sincosf(ang, &s, &c);
        hb[e] = (_Float16)((n < 129) ? c : s);
      }
      bf[i][kk] = hb;
    }
  }

  int r0 = blockIdx.x * PSD_ROWS;
  float4 v[4];
  // prologue: load + stage row 0 (rowm slot 0), then load row 1
  {
    const float* xr = x + (size_t)r0 * T_LEN;
    #pragma unroll
    for (int j = 0; j < 4; ++j) {
      int c = tid + 512 * j;
      v[j] = (c < 1500) ? ((const float4*)xr)[c] : make_float4(0.f, 0.f, 0.f, 0.f);
    }
    float rs = 0.f;
    #pragma unroll
    for (int j = 0; j < 4; ++j) {
      int c = tid + 512 * j;
      if (c < 1568) {
        float4 q = v[j];
        rs += q.x + q.y + q.z + q.w;
        half4_t h = { (_Float16)q.x, (_Float16)q.y, (_Float16)q.z, (_Float16)q.w };
        int byte = 8 * c;
        byte ^= ((byte >> 8) & 7) << 4;
        *(half4_t*)((char*)xh[0] + byte) = h;
      }
    }
    #pragma unroll
    for (int off = 32; off >= 1; off >>= 1) rs += __shfl_xor(rs, off);
    if (lane == 0) rowm[0][w] = rs;
    const float* x1 = x + (size_t)(r0 + 1) * T_LEN;
    #pragma unroll
    for (int j = 0; j < 4; ++j) {
      int c = tid + 512 * j;
      v[j] = (c < 1500) ? ((const float4*)x1)[c] : make_float4(0.f, 0.f, 0.f, 0.f);
    }
  }
  __syncthreads();                              // xh[0] visible

  for (int jr = 0; jr < PSD_ROWS; ++jr) {
    int r = r0 + jr;
    const char* xcur = (const char*)xh[jr & 1];
    // ---- phase 1: stage row jr+1 into other buffer; issue loads row jr+2 ----
    if (jr + 1 < PSD_ROWS) {
      char* xnxt = (char*)xh[(jr + 1) & 1];
      float rs = 0.f;
      #pragma unroll
      for (int j = 0; j < 4; ++j) {
        int c = tid + 512 * j;
        if (c < 1568) {
          float4 q = v[j];
          rs += q.x + q.y + q.z + q.w;
          half4_t h = { (_Float16)q.x, (_Float16)q.y, (_Float16)q.z, (_Float16)q.w };
          int byte = 8 * c;
          byte ^= ((byte >> 8) & 7) << 4;
          *(half4_t*)(xnxt + byte) = h;
        }
      }
      if (jr + 2 < PSD_ROWS) {
        const float* xn = x + (size_t)(r + 2) * T_LEN;
        #pragma unroll
        for (int j = 0; j < 4; ++j) {
          int c = tid + 512 * j;
          v[j] = (c < 1500) ? ((const float4*)xn)[c] : make_float4(0.f, 0.f, 0.f, 0.f);
        }
      }
      #pragma unroll
      for (int off = 32; off >= 1; off >>= 1) rs += __shfl_xor(rs, off);
      if (lane == 0) rowm[(jr + 1) % 3][w] = rs;
    }
    // ---- GEMM on xcur (overlaps the stage/load latency above) ----
    f32x4 acc[2][3];
    #pragma unroll
    for (int i = 0; i < 2; ++i)
      #pragma unroll
      for (int mt = 0; mt < 3; ++mt)
        acc[i][mt] = (f32x4){0.f, 0.f, 0.f, 0.f};
    #pragma unroll
    for (int kk = 0; kk < 8; ++kk) {
      half8 a[3];
      #pragma unroll
      for (int mt = 0; mt < 3; ++mt) {
        int ab = 4096 * mt + 256 * l15 + 64 * kk + 16 * l4;
        ab ^= ((ab >> 8) & 7) << 4;
        a[mt] = *(const half8*)(xcur + ab);
      }
      #pragma unroll
      for (int mt = 0; mt < 3; ++mt) {
        acc[0][mt] = __builtin_amdgcn_mfma_f32_16x16x32_f16(a[mt], bf[0][kk], acc[0][mt], 0, 0, 0);
        acc[1][mt] = __builtin_amdgcn_mfma_f32_16x16x32_f16(a[mt], bf[1][kk], acc[1][mt], 0, 0, 0);
      }
    }
    // per-lane column partials; C/D: row m = 16*mt+4*l4+j, col n = 16*nt+l15
    float s0, s1;
    #pragma unroll
    for (int i = 0; i < 2; ++i) {
      float t = 0.f;
      #pragma unroll
      for (int j = 0; j < 4; ++j) {
        t += acc[i][0][j] * acc[i][0][j];
        t += acc[i][1][j] * acc[i][1][j];
        if (4 * l4 + j < 13) t += acc[i][2][j] * acc[i][2][j];  // mask m>=45
      }
      t += __shfl_xor(t, 16);
      t += __shfl_xor(t, 32);
      if (i == 0) s0 = t; else s1 = t;
    }
    __syncthreads();                            // (A) stage visible, GEMM reads done
    if (l4 == 0) {
      colsum[16 * (2 * w + 0) + l15] = s0;
      colsum[16 * (2 * w + 1) + l15] = s1;
    }
    __syncthreads();                            // (B) colsum visible
    if (tid < F_BINS) {
      float vv;
      if (tid == 0) vv = 0.f;                                   // detrended DC
      else if (tid == 128) vv = colsum[128] * (1.f / 11520.f);  // Nyquist, no doubling
      else vv = (colsum[tid] + colsum[tid + 128]) * (1.f / 5760.f);
      psd[(size_t)r * F_BINS + tid] = vv + REG_EPS;
    }
    if (tid == 0) {
      float ms = 0.f;
      #pragma unroll
      for (int q = 0; q < 8; ++q) ms += rowm[jr % 3][q];
      means[r] = ms * (1.f / (float)T_LEN);
    }
  }
}

// ---------------- Kernel C: barycenter over batch (unchanged) ----------------
__global__ __launch_bounds__(256) void bary_kernel(const float* __restrict__ psd,
                                                   float* __restrict__ bary) {
  int cf = blockIdx.x;
  int tid = threadIdx.x;
  float s = sqrtf(psd[(size_t)tid * CF + cf]) +
            sqrtf(psd[(size_t)(tid + 256) * CF + cf]);
  #pragma unroll
  for (int off = 32; off >= 1; off >>= 1) s += __shfl_down(s, off);
  __shared__ float wsum[4];
  if ((tid & 63) == 0) wsum[tid >> 6] = s;
  __syncthreads();
  if (tid == 0) {
    float tot = (wsum[0] + wsum[1] + wsum[2] + wsum[3]) * (1.f / (float)F_BINS);
    bary[cf] = tot * tot;
  }
}

// ---------------- Kernel D: filter H (unchanged) ----------------
__global__ __launch_bounds__(256) void filt_kernel(const float* __restrict__ psd,
                                                   const float* __restrict__ bary,
                                                   float* __restrict__ H) {
  int rc = blockIdx.x;
  int c = rc & (NCH - 1);
  int t = threadIdx.x;
  __shared__ float dv[F_BINS];
  __shared__ float hv[F_BINS];
  if (t < F_BINS)
    dv[t] = sqrtf(bary[c * F_BINS + t] / psd[(size_t)rc * F_BINS + t]);
  __syncthreads();
  if (t < F_BINS) {
    float ct, st;
    __sincosf(6.283185307179586f * (float)t * (1.f / 256.f), &st, &ct);
    float cr = ct, ci = st;
    float acc = 0.f;
    for (int k = 1; k <= 127; ++k) {
      acc = fmaf(dv[k], cr, acc);
      float nr = cr * ct - ci * st;
      ci = cr * st + ci * ct;
      cr = nr;
    }
    float val = dv[0] + ((t & 1) ? -dv[128] : dv[128]) + 2.f * acc;
    hv[t] = val * (1.f / 256.f);
  }
  __syncthreads();
  int idx = t - 127; if (idx < 0) idx = -idx;
  H[(size_t)rc * 256 + t] = hv[idx];
}

// ---------------- Kernel E: depthwise conv as per-row im2col MFMA GEMM ----------------
// GEMM body unchanged. NEW: coalesced y stores via LDS bounce -- each wave's 4 tiles
// are y[1024w..1024w+1024) contiguous; after a post-GEMM barrier the smem (xh+Bp,
// no longer needed) is reused: lane scatters its 16 acc values into the wave's 4KB
// region, then stores 4 fully-coalesced dwordx4 (1KB/wave/instr). Within-wave LDS
// RAW needs no barrier.
#define XH_N 6528
#define BSTRIDE 296
__global__ __launch_bounds__(384, 1) void conv_kernel(const float* __restrict__ x,
                                                      const float* __restrict__ means,
                                                      const float* __restrict__ Hg,
                                                      float* __restrict__ y) {
  int rc = blockIdx.x;
  int tid = threadIdx.x;
  int lane = tid & 63;
  int w = tid >> 6;
  __shared__ __align__(16) char smem[24576];
  _Float16* xh = (_Float16*)smem;                 // 13056 B
  _Float16* Bp = (_Float16*)(smem + 13056);       //  9472 B (ends 22528)
  const float* xr = x + (size_t)rc * T_LEN;
  const float* Hrow = Hg + (size_t)rc * 256;
  float mean = means[rc];
  // xh: half4 chunk q covers halves [4q,4q+4) = x float4 chunk q-32 (minus mean)
  #pragma unroll
  for (int j = 0; j < 5; ++j) {
    int q = tid + 384 * j;
    if (q < 1632) {
      int c = q - 32;
      half4_t h;
      if (c >= 0 && c < 1500) {
        float4 vv = ((const float4*)xr)[c];
        h = (half4_t){ (_Float16)(vv.x - mean), (_Float16)(vv.y - mean),
                       (_Float16)(vv.z - mean), (_Float16)(vv.w - mean) };
      } else {
        h = (half4_t){ (_Float16)0.f, (_Float16)0.f, (_Float16)0.f, (_Float16)0.f };
      }
      *(half4_t*)((char*)xh + 8 * q) = h;
    }
  }
  // Bp: idx = chunk*16+n; thread writes half4 at Bp[n][4*qq..] = H[4*qq-n-1 ..]
  #pragma unroll
  for (int j = 0; j < 3; ++j) {
    int idx = tid + 384 * j;        // < 1152 = 72*16 exactly
    int n = idx & 15;
    int qq = idx >> 4;              // 0..71
    int s0 = 4 * qq - n - 1;
    half4_t h;
    #pragma unroll
    for (int e = 0; e < 4; ++e) {
      int s = s0 + e;
      float hv = (s >= 0 && s < 256) ? Hrow[s] : 0.f;
      h[e] = (_Float16)hv;
    }
    *(half4_t*)((char*)Bp + (size_t)n * (2 * BSTRIDE) + 8 * qq) = h;
  }
  __syncthreads();

  int l15 = lane & 15, l4 = lane >> 4;
  f32x4 acc0 = {0.f,0.f,0.f,0.f}, acc1 = {0.f,0.f,0.f,0.f};
  f32x4 acc2 = {0.f,0.f,0.f,0.f}, acc3 = {0.f,0.f,0.f,0.f};
  const _Float16* bbase = &Bp[BSTRIDE * l15 + 8 * l4];
  const _Float16* abase = &xh[16 * l15 + 8 * l4 + 1024 * w];
  #pragma unroll
  for (int kk = 0; kk < 9; ++kk) {
    half8 b = *(const half8*)(bbase + 32 * kk);
    half8 a0 = *(const half8*)(abase + 32 * kk);
    half8 a1 = *(const half8*)(abase + 256 + 32 * kk);
    half8 a2 = *(const half8*)(abase + 512 + 32 * kk);
    half8 a3 = *(const half8*)(abase + 768 + 32 * kk);
    acc0 = __builtin_amdgcn_mfma_f32_16x16x32_f16(a0, b, acc0, 0, 0, 0);
    acc1 = __builtin_amdgcn_mfma_f32_16x16x32_f16(a1, b, acc1, 0, 0, 0);
    acc2 = __builtin_amdgcn_mfma_f32_16x16x32_f16(a2, b, acc2, 0, 0, 0);
    acc3 = __builtin_amdgcn_mfma_f32_16x16x32_f16(a3, b, acc3, 0, 0, 0);
  }
  __syncthreads();                 // all GEMM LDS reads done; smem reusable
  // bounce: wave w's region = floats [1024w, 1024w+1024)
  float* bw = (float*)smem + 1024 * w;
  #pragma unroll
  for (int i = 0; i < 4; ++i) {
    f32x4 a = (i == 0) ? acc0 : (i == 1) ? acc1 : (i == 2) ? acc2 : acc3;
    #pragma unroll
    for (int j = 0; j < 4; ++j)
      bw[256 * i + 64 * l4 + 16 * j + l15] = a[j];
  }
  // coalesced store: lane reads its own wave's region (within-wave dep, no barrier)
  float* yr = y + (size_t)rc * T_LEN + 1024 * w;
  const float4* b4 = (const float4*)bw;
  #pragma unroll
  for (int c = 0; c < 4; ++c) {
    int fi = 1024 * w + 256 * c + 4 * lane;
    if (fi < T_LEN)
      *(float4*)&yr[256 * c + 4 * lane] = b4[64 * c + lane];
  }
}

extern "C" void kernel_launch(void* const* d_in, const int* in_sizes, int n_in,
                              void* d_out, int out_size, void* d_ws, size_t ws_size,
                              hipStream_t stream) {
  const float* x = (const float*)d_in[0];
  float* out = (float*)d_out;
  float* psd   = (float*)d_ws;                         //   528,384 f
  float* bary  = psd + (size_t)NROWS * F_BINS;         //     1,032 f
  float* H     = bary + CF;                            // 1,048,576 f
  float* means = H + (size_t)NROWS * 256;              //     4,096 f
  psd_kernel<<<NROWS / PSD_ROWS, 512, 0, stream>>>(x, psd, means);
  bary_kernel<<<CF, 256, 0, stream>>>(psd, bary);
  filt_kernel<<<NROWS, 256, 0, stream>>>(psd, bary, H);
  conv_kernel<<<NROWS, 384, 0, stream>>>(x, means, H, out);
}

// Round 14
// 97.875 us; speedup vs baseline: 1.7375x; 1.2084x over previous
//
#include <hip/hip_runtime.h>
#include <math.h>

#define T_LEN 6000
#define NROWS 4096          // B*C = 512*8
#define NCH 8
#define F_BINS 129
#define CF (NCH*F_BINS)     // 1032
#define REG_EPS 1e-7f

typedef _Float16 half8 __attribute__((ext_vector_type(8)));
typedef _Float16 half4_t __attribute__((ext_vector_type(4)));
typedef float f32x4 __attribute__((ext_vector_type(4)));

// ---------------- Kernel B: Welch PSD + row mean via im2col MFMA GEMM ----------------
// 8 waves; wave w owns N-tiles {2w,2w+1}; bf[2][8] persistent, computed IN-KERNEL.
// DOUBLE-BUFFERED LDS pipeline (2 barriers/row).
// __launch_bounds__(512,2): (512,4) capped VGPR at 64 and spilled (round-11 evidence).
#define PSD_ROWS 8
__global__ __launch_bounds__(512, 2) void psd_kernel(const float* __restrict__ x,
                                                     float* __restrict__ psd,
                                                     float* __restrict__ means) {
  int tid = threadIdx.x;
  int lane = tid & 63;
  int w = tid >> 6;          // 0..7
  int l15 = lane & 15, l4 = lane >> 4;
  __shared__ __align__(16) _Float16 xh[2][6272];
  __shared__ float colsum[256];
  __shared__ float rowm[3][8];

  // persistent B fragments: nt = 2w+i, col n = 16*nt+l15, k = 32*kk+8*l4+e
  half8 bf[2][8];
  #pragma unroll
  for (int i = 0; i < 2; ++i) {
    int n = 16 * (2 * w + i) + l15;
    int nn = (n < 129) ? n : (n - 128);
    for (int kk = 0; kk < 8; ++kk) {
      half8 hb;
      for (int e = 0; e < 8; ++e) {
        int k = 32 * kk + 8 * l4 + e;
        float ang = (float)((nn * k) & 255) * (6.283185307179586f / 256.f);
        float s, c;
        __sincosf(ang, &s, &c);
        hb[e] = (_Float16)((n < 129) ? c : s);
      }
      bf[i][kk] = hb;
    }
  }

  int r0 = blockIdx.x * PSD_ROWS;
  float4 v[4];
  // prologue: load + stage row 0 (rowm slot 0), then load row 1
  {
    const float* xr = x + (size_t)r0 * T_LEN;
    #pragma unroll
    for (int j = 0; j < 4; ++j) {
      int c = tid + 512 * j;
      v[j] = (c < 1500) ? ((const float4*)xr)[c] : make_float4(0.f, 0.f, 0.f, 0.f);
    }
    float rs = 0.f;
    #pragma unroll
    for (int j = 0; j < 4; ++j) {
      int c = tid + 512 * j;
      if (c < 1568) {
        float4 q = v[j];
        rs += q.x + q.y + q.z + q.w;
        half4_t h = { (_Float16)q.x, (_Float16)q.y, (_Float16)q.z, (_Float16)q.w };
        int byte = 8 * c;
        byte ^= ((byte >> 8) & 7) << 4;
        *(half4_t*)((char*)xh[0] + byte) = h;
      }
    }
    #pragma unroll
    for (int off = 32; off >= 1; off >>= 1) rs += __shfl_xor(rs, off);
    if (lane == 0) rowm[0][w] = rs;
    const float* x1 = x + (size_t)(r0 + 1) * T_LEN;
    #pragma unroll
    for (int j = 0; j < 4; ++j) {
      int c = tid + 512 * j;
      v[j] = (c < 1500) ? ((const float4*)x1)[c] : make_float4(0.f, 0.f, 0.f, 0.f);
    }
  }
  __syncthreads();                              // xh[0] visible

  for (int jr = 0; jr < PSD_ROWS; ++jr) {
    int r = r0 + jr;
    const char* xcur = (const char*)xh[jr & 1];
    // ---- phase 1: stage row jr+1 into other buffer; issue loads row jr+2 ----
    if (jr + 1 < PSD_ROWS) {
      char* xnxt = (char*)xh[(jr + 1) & 1];
      float rs = 0.f;
      #pragma unroll
      for (int j = 0; j < 4; ++j) {
        int c = tid + 512 * j;
        if (c < 1568) {
          float4 q = v[j];
          rs += q.x + q.y + q.z + q.w;
          half4_t h = { (_Float16)q.x, (_Float16)q.y, (_Float16)q.z, (_Float16)q.w };
          int byte = 8 * c;
          byte ^= ((byte >> 8) & 7) << 4;
          *(half4_t*)(xnxt + byte) = h;
        }
      }
      if (jr + 2 < PSD_ROWS) {
        const float* xn = x + (size_t)(r + 2) * T_LEN;
        #pragma unroll
        for (int j = 0; j < 4; ++j) {
          int c = tid + 512 * j;
          v[j] = (c < 1500) ? ((const float4*)xn)[c] : make_float4(0.f, 0.f, 0.f, 0.f);
        }
      }
      #pragma unroll
      for (int off = 32; off >= 1; off >>= 1) rs += __shfl_xor(rs, off);
      if (lane == 0) rowm[(jr + 1) % 3][w] = rs;
    }
    // ---- GEMM on xcur (overlaps the stage/load latency above) ----
    f32x4 acc[2][3];
    #pragma unroll
    for (int i = 0; i < 2; ++i)
      #pragma unroll
      for (int mt = 0; mt < 3; ++mt)
        acc[i][mt] = (f32x4){0.f, 0.f, 0.f, 0.f};
    #pragma unroll
    for (int kk = 0; kk < 8; ++kk) {
      half8 a[3];
      #pragma unroll
      for (int mt = 0; mt < 3; ++mt) {
        int ab = 4096 * mt + 256 * l15 + 64 * kk + 16 * l4;
        ab ^= ((ab >> 8) & 7) << 4;
        a[mt] = *(const half8*)(xcur + ab);
      }
      #pragma unroll
      for (int mt = 0; mt < 3; ++mt) {
        acc[0][mt] = __builtin_amdgcn_mfma_f32_16x16x32_f16(a[mt], bf[0][kk], acc[0][mt], 0, 0, 0);
        acc[1][mt] = __builtin_amdgcn_mfma_f32_16x16x32_f16(a[mt], bf[1][kk], acc[1][mt], 0, 0, 0);
      }
    }
    // per-lane column partials; C/D: row m = 16*mt+4*l4+j, col n = 16*nt+l15
    float s0, s1;
    #pragma unroll
    for (int i = 0; i < 2; ++i) {
      float t = 0.f;
      #pragma unroll
      for (int j = 0; j < 4; ++j) {
        t += acc[i][0][j] * acc[i][0][j];
        t += acc[i][1][j] * acc[i][1][j];
        if (4 * l4 + j < 13) t += acc[i][2][j] * acc[i][2][j];  // mask m>=45
      }
      t += __shfl_xor(t, 16);
      t += __shfl_xor(t, 32);
      if (i == 0) s0 = t; else s1 = t;
    }
    __syncthreads();                            // (A) stage visible, GEMM reads done
    if (l4 == 0) {
      colsum[16 * (2 * w + 0) + l15] = s0;
      colsum[16 * (2 * w + 1) + l15] = s1;
    }
    __syncthreads();                            // (B) colsum visible
    if (tid < F_BINS) {
      float vv;
      if (tid == 0) vv = 0.f;                                   // detrended DC
      else if (tid == 128) vv = colsum[128] * (1.f / 11520.f);  // Nyquist, no doubling
      else vv = (colsum[tid] + colsum[tid + 128]) * (1.f / 5760.f);
      psd[(size_t)r * F_BINS + tid] = vv + REG_EPS;
    }
    if (tid == 0) {
      float ms = 0.f;
      #pragma unroll
      for (int q = 0; q < 8; ++q) ms += rowm[jr % 3][q];
      means[r] = ms * (1.f / (float)T_LEN);
    }
  }
}

// ---------------- Kernel C: barycenter over batch (unchanged) ----------------
__global__ __launch_bounds__(256) void bary_kernel(const float* __restrict__ psd,
                                                   float* __restrict__ bary) {
  int cf = blockIdx.x;
  int tid = threadIdx.x;
  float s = sqrtf(psd[(size_t)tid * CF + cf]) +
            sqrtf(psd[(size_t)(tid + 256) * CF + cf]);
  #pragma unroll
  for (int off = 32; off >= 1; off >>= 1) s += __shfl_down(s, off);
  __shared__ float wsum[4];
  if ((tid & 63) == 0) wsum[tid >> 6] = s;
  __syncthreads();
  if (tid == 0) {
    float tot = (wsum[0] + wsum[1] + wsum[2] + wsum[3]) * (1.f / (float)F_BINS);
    bary[cf] = tot * tot;
  }
}

// ---------------- Kernel E: conv with FUSED filter construction ----------------
// filt_kernel folded in: dv[t]=sqrt(bary[c,t]/psd[rc,t]); hv[t]=irfft rotation sum;
// H[s]=hv[|s-127|] consumed straight into the Bp panel. Removes one kernel launch,
// its gap, and the 8MB H round-trip. dv/hv live in the spare smem after Bp.
#define BSTRIDE 296
__global__ __launch_bounds__(384) void conv_kernel(const float* __restrict__ x,
                                                   const float* __restrict__ means,
                                                   const float* __restrict__ psd,
                                                   const float* __restrict__ bary,
                                                   float* __restrict__ y) {
  int rc = blockIdx.x;
  int c = rc & (NCH - 1);
  int tid = threadIdx.x;
  int lane = tid & 63;
  int w = tid >> 6;
  __shared__ __align__(16) char smem[24576];
  _Float16* xh = (_Float16*)smem;                 // [0, 13056)
  _Float16* Bp = (_Float16*)(smem + 13056);       // [13056, 22528)
  float* dv = (float*)(smem + 22528);             // [22528, 23044)
  float* hv = (float*)(smem + 23044);             // [23044, 23560)
  const float* xr = x + (size_t)rc * T_LEN;
  float mean = means[rc];
  // dv (issue these global loads first; compute overlaps xh staging below)
  if (tid < F_BINS)
    dv[tid] = sqrtf(bary[c * F_BINS + tid] / psd[(size_t)rc * F_BINS + tid]);
  // xh: half4 chunk q covers halves [4q,4q+4) = x float4 chunk q-32 (minus mean)
  #pragma unroll
  for (int j = 0; j < 5; ++j) {
    int q = tid + 384 * j;
    if (q < 1632) {
      int cc = q - 32;
      half4_t h;
      if (cc >= 0 && cc < 1500) {
        float4 vv = ((const float4*)xr)[cc];
        h = (half4_t){ (_Float16)(vv.x - mean), (_Float16)(vv.y - mean),
                       (_Float16)(vv.z - mean), (_Float16)(vv.w - mean) };
      } else {
        h = (half4_t){ (_Float16)0.f, (_Float16)0.f, (_Float16)0.f, (_Float16)0.f };
      }
      *(half4_t*)((char*)xh + 8 * q) = h;
    }
  }
  __syncthreads();                                // dv (and xh) visible
  // hv[t] = (dv0 + (-1)^t dv128 + 2*sum_{k=1}^{127} dvk cos(2pi k t/256)) / 256
  if (tid < F_BINS) {
    float ct, st;
    __sincosf(6.283185307179586f * (float)tid * (1.f / 256.f), &st, &ct);
    float cr = ct, ci = st;
    float acc = 0.f;
    for (int k = 1; k <= 127; ++k) {
      acc = fmaf(dv[k], cr, acc);
      float nr = cr * ct - ci * st;
      ci = cr * st + ci * ct;
      cr = nr;
    }
    float val = dv[0] + ((tid & 1) ? -dv[128] : dv[128]) + 2.f * acc;
    hv[tid] = val * (1.f / 256.f);
  }
  __syncthreads();                                // hv visible
  // Bp[n][4qq+e] = H[s]=hv[|s-127|], s=4qq-n-1+e (0 outside [0,256))
  #pragma unroll
  for (int j = 0; j < 3; ++j) {
    int idx = tid + 384 * j;        // < 1152 = 72*16 exactly
    int n = idx & 15;
    int qq = idx >> 4;              // 0..71
    int s0 = 4 * qq - n - 1;
    half4_t h;
    #pragma unroll
    for (int e = 0; e < 4; ++e) {
      int s = s0 + e;
      float hvv = 0.f;
      if (s >= 0 && s < 256) {
        int ii = s - 127; if (ii < 0) ii = -ii;
        hvv = hv[ii];
      }
      h[e] = (_Float16)hvv;
    }
    *(half4_t*)((char*)Bp + (size_t)n * (2 * BSTRIDE) + 8 * qq) = h;
  }
  __syncthreads();

  int l15 = lane & 15, l4 = lane >> 4;
  f32x4 acc0 = {0.f,0.f,0.f,0.f}, acc1 = {0.f,0.f,0.f,0.f};
  f32x4 acc2 = {0.f,0.f,0.f,0.f}, acc3 = {0.f,0.f,0.f,0.f};
  const _Float16* bbase = &Bp[BSTRIDE * l15 + 8 * l4];
  const _Float16* abase = &xh[16 * l15 + 8 * l4 + 1024 * w];
  #pragma unroll
  for (int kk = 0; kk < 9; ++kk) {
    half8 b = *(const half8*)(bbase + 32 * kk);
    half8 a0 = *(const half8*)(abase + 32 * kk);
    half8 a1 = *(const half8*)(abase + 256 + 32 * kk);
    half8 a2 = *(const half8*)(abase + 512 + 32 * kk);
    half8 a3 = *(const half8*)(abase + 768 + 32 * kk);
    acc0 = __builtin_amdgcn_mfma_f32_16x16x32_f16(a0, b, acc0, 0, 0, 0);
    acc1 = __builtin_amdgcn_mfma_f32_16x16x32_f16(a1, b, acc1, 0, 0, 0);
    acc2 = __builtin_amdgcn_mfma_f32_16x16x32_f16(a2, b, acc2, 0, 0, 0);
    acc3 = __builtin_amdgcn_mfma_f32_16x16x32_f16(a3, b, acc3, 0, 0, 0);
  }
  __syncthreads();                 // all GEMM LDS reads done; smem reusable
  // bounce: wave w's region = floats [1024w, 1024w+1024)
  float* bw = (float*)smem + 1024 * w;
  #pragma unroll
  for (int i = 0; i < 4; ++i) {
    f32x4 a = (i == 0) ? acc0 : (i == 1) ? acc1 : (i == 2) ? acc2 : acc3;
    #pragma unroll
    for (int j = 0; j < 4; ++j)
      bw[256 * i + 64 * l4 + 16 * j + l15] = a[j];
  }
  // coalesced store: lane reads its own wave's region (within-wave dep, no barrier)
  float* yr = y + (size_t)rc * T_LEN + 1024 * w;
  const float4* b4 = (const float4*)bw;
  #pragma unroll
  for (int cc = 0; cc < 4; ++cc) {
    int fi = 1024 * w + 256 * cc + 4 * lane;
    if (fi < T_LEN)
      *(float4*)&yr[256 * cc + 4 * lane] = b4[64 * cc + lane];
  }
}

extern "C" void kernel_launch(void* const* d_in, const int* in_sizes, int n_in,
                              void* d_out, int out_size, void* d_ws, size_t ws_size,
                              hipStream_t stream) {
  const float* x = (const float*)d_in[0];
  float* out = (float*)d_out;
  float* psd   = (float*)d_ws;                         //   528,384 f
  float* bary  = psd + (size_t)NROWS * F_BINS;         //     1,032 f
  float* means = bary + CF;                            //     4,096 f
  psd_kernel<<<NROWS / PSD_ROWS, 512, 0, stream>>>(x, psd, means);
  bary_kernel<<<CF, 256, 0, stream>>>(psd, bary);
  conv_kernel<<<NROWS, 384, 0, stream>>>(x, means, psd, bary, out);
}